// Round 2
// baseline (528.301 us; speedup 1.0000x reference)
//
#include <hip/hip_runtime.h>
#include <math.h>

#define DIMN 96
#define SLICE 9216           // 96*96
#define VOL 884736           // 96^3
#define NB 2
#define KK 3
#define BIGI VOL             // reference BIGI = V
#define INF16 60000          // ushort "infinity"; real d^2 <= 3*95^2 = 27075
#define LSTR 97              // padded LDS row stride (bank-conflict-free)
#define NPART 192            // partial-sum rows (NB*96)
#define CC_SWEEPS 8          // pointer-jumping: reach >= 3^t growth, need 18

// ---- workspace layout (bytes) ----
#define OFF_ACT   (NB*VOL*4)
#define OFF_DIST  (2*NB*VOL*4)
#define OFF_SMALL (OFF_DIST + NB*KK*VOL*4)   // dist region oversized (ushort now)
#define OFF_ROOTS (OFF_SMALL + 32)
#define OFF_UL    (OFF_ROOTS + 2*64*4)
#define OFF_PART  (OFF_SMALL + 1024)

__global__ void k_zero_small(int* small) {
  if (threadIdx.x < 8) small[threadIdx.x] = 0;
}

// lab init + active masked-voxel list
__global__ void k_init(const float* __restrict__ tgt, int* __restrict__ lab,
                       int* __restrict__ act, int* __restrict__ small) {
  int idx = blockIdx.x * 256 + threadIdx.x;
  if (idx >= NB * VOL) return;
  int v = (idx >= VOL) ? idx - VOL : idx;
  if (tgt[idx] > 0.5f) {
    lab[idx] = v;
    int pos = atomicAdd(&small[0], 1);
    act[pos] = idx;
  } else {
    lab[idx] = BIGI;
  }
}

// chaotic min-propagation sweep + double pointer-jump (shortcutting).
// Invariants: lab[v] monotonically decreases, always holds the index of a
// masked voxel in v's component, lab[v] <= v. Reach grows >= 3x+1 per sweep.
// Last sweep (record=1) also records converged roots (lab[v]==v).
__global__ void k_prop(int* __restrict__ lab, const int* __restrict__ act,
                       int* __restrict__ small, int record,
                       int* __restrict__ roots) {
  int n = small[0];
  for (int i = blockIdx.x * blockDim.x + threadIdx.x; i < n;
       i += gridDim.x * blockDim.x) {
    int idx = act[i];
    int bo = (idx >= VOL) ? VOL : 0;
    int v = idx - bo;
    int z = v / SLICE;
    int rem = v - z * SLICE;
    int y = rem / DIMN;
    int x = rem - y * DIMN;
    int* L = lab + bo;
    int z0 = z > 0 ? z - 1 : 0, z1 = z < 95 ? z + 1 : 95;
    int y0 = y > 0 ? y - 1 : 0, y1 = y < 95 ? y + 1 : 95;
    int x0 = x > 0 ? x - 1 : 0, x1 = x < 95 ? x + 1 : 95;
    int m = BIGI;
    for (int zz = z0; zz <= z1; zz++)
      for (int yy = y0; yy <= y1; yy++) {
        const int* row = L + zz * SLICE + yy * DIMN;
        for (int xx = x0; xx <= x1; xx++) m = min(m, row[xx]);
      }
    // m < BIGI always (self included). Two shortcut jumps.
    int m2 = L[m];
    int m3 = L[m2];
    lab[idx] = m3;
    if (record && m3 == v) {
      int b = bo ? 1 : 0;
      int pos = atomicAdd(&small[1 + b], 1);
      if (pos < 64) roots[b * 64 + pos] = v;
    }
  }
}

// K smallest roots per batch (== jnp.unique(lab, size=K+1)[:K] semantics)
__global__ void k_select(const int* __restrict__ small, int* __restrict__ roots,
                         int* __restrict__ ul) {
  if (threadIdx.x != 0 || blockIdx.x != 0) return;
  for (int b = 0; b < NB; b++) {
    int n = small[1 + b];
    if (n > 64) n = 64;
    for (int k = 0; k < KK; k++) {
      int best = 0x7fffffff, bi = -1;
      for (int j = 0; j < n; j++) {
        int r = roots[b * 64 + j];
        if (r < best) { best = r; bi = j; }
      }
      if (bi >= 0) { ul[b * 4 + k] = best; roots[b * 64 + bi] = 0x7fffffff; }
      else         { ul[b * 4 + k] = BIGI; }
    }
  }
}

// One block per (b,z) slice. For each k: seed map from lab (in LDS),
// x-pass two-scan (seeds are 0/INF), y-pass Felzenszwalb lower envelope,
// write ushort dist. All strided access stays in LDS; global I/O coalesced.
__global__ __launch_bounds__(256) void k_edt_xy(const int* __restrict__ lab,
                                                const int* __restrict__ ul,
                                                unsigned short* __restrict__ dist) {
  __shared__ unsigned short dl[96 * LSTR];   // 18624 B, d[y][i]
  __shared__ float zb[97 * 96];              // 37248 B, hull boundaries [idx][line]
  __shared__ unsigned char vb[96 * 96];      //  9216 B, hull vertices  [idx][line]
  int blk = blockIdx.x;
  int b = blk / 96, z = blk - b * 96;
  const int* L = lab + b * VOL + z * SLICE;
  int t = threadIdx.x;
  for (int k = 0; k < KK; k++) {
    int ulk = ul[b * 4 + k];
    __syncthreads();                          // prev k's y-pass done with dl
    for (int i = t; i < SLICE; i += 256) {
      int row = i / 96, col = i - row * 96;
      dl[row * LSTR + col] = (L[i] == ulk) ? 1 : 0;
    }
    __syncthreads();
    if (t < 96) {                             // x-pass: thread = y line
      unsigned short* R = dl + t * LSTR;
      unsigned long long mlo = 0, mhi = 0;    // seed bitmask for backward scan
      int last = -1;
      for (int i = 0; i < 96; i++) {
        if (R[i]) {
          last = i;
          if (i < 64) mlo |= 1ull << i; else mhi |= 1ull << (i - 64);
        }
        int d = i - last;
        R[i] = (last < 0) ? (unsigned short)INF16 : (unsigned short)(d * d);
      }
      last = 200;
      for (int i = 95; i >= 0; i--) {
        int seed = (i < 64) ? (int)((mlo >> i) & 1) : (int)((mhi >> (i - 64)) & 1);
        if (seed) last = i;
        if (last <= 95) {
          int dd = (last - i) * (last - i);
          if (dd < (int)R[i]) R[i] = (unsigned short)dd;
        }
      }
    }
    __syncthreads();
    if (t < 96) {                             // y-pass: thread = x column
      int x = t;
      float* Z = zb + x;
      unsigned char* Vv = vb + x;
      int kk = 0;
      Vv[0] = 0; Z[0] = -3e38f; Z[96] = 3e38f;
      for (int q = 1; q < 96; q++) {
        int fq = (int)dl[q * LSTR + x] + q * q;
        float s;
        while (1) {
          int vk = Vv[kk * 96];
          int fvk = (int)dl[vk * LSTR + x] + vk * vk;
          s = (float)(fq - fvk) / (float)(2 * (q - vk));
          if (kk > 0 && s <= Z[kk * 96]) { kk--; } else break;
        }
        kk++;
        Vv[kk * 96] = (unsigned char)q;
        Z[kk * 96] = s;
        Z[(kk + 1) * 96] = 3e38f;
      }
      unsigned short* D = dist + (size_t)(b * KK + k) * VOL + z * SLICE + x;
      int j = 0;
      for (int q = 0; q < 96; q++) {
        float fq = (float)q;
        while (Z[(j + 1) * 96] < fq) j++;
        int vj = Vv[j * 96];
        int dq = q - vj;
        int val = (int)dl[vj * LSTR + x] + dq * dq;
        D[q * 96] = (unsigned short)min(val, INF16);
      }
    }
  }
}

// One block per (b,y) slab. Phase A per k: load [z][x] slab, Felzenszwalb
// along z, write final dist back in place. Phase B: argmin over k (tie ->
// lowest k, matching jnp.argmin), sigmoid, partial dice sums.
__global__ __launch_bounds__(256) void k_edt_z_fuse(unsigned short* __restrict__ dist,
                                                    const float* __restrict__ pred,
                                                    const float* __restrict__ tgt,
                                                    float* __restrict__ part) {
  __shared__ unsigned short dl[96 * LSTR];
  __shared__ float zb[97 * 96];
  __shared__ unsigned char vb[96 * 96];
  __shared__ float wsum[4][9];
  int blk = blockIdx.x;
  int b = blk / 96, y = blk - b * 96;
  int t = threadIdx.x;
  for (int k = 0; k < KK; k++) {
    unsigned short* D = dist + (size_t)(b * KK + k) * VOL + y * 96;
    __syncthreads();
    for (int i = t; i < SLICE; i += 256) {
      int zz = i / 96, xx = i - zz * 96;
      dl[zz * LSTR + xx] = D[zz * SLICE + xx];
    }
    __syncthreads();
    if (t < 96) {                             // z-pass: thread = x column
      int x = t;
      float* Z = zb + x;
      unsigned char* Vv = vb + x;
      int kk = 0;
      Vv[0] = 0; Z[0] = -3e38f; Z[96] = 3e38f;
      for (int q = 1; q < 96; q++) {
        int fq = (int)dl[q * LSTR + x] + q * q;
        float s;
        while (1) {
          int vk = Vv[kk * 96];
          int fvk = (int)dl[vk * LSTR + x] + vk * vk;
          s = (float)(fq - fvk) / (float)(2 * (q - vk));
          if (kk > 0 && s <= Z[kk * 96]) { kk--; } else break;
        }
        kk++;
        Vv[kk * 96] = (unsigned char)q;
        Z[kk * 96] = s;
        Z[(kk + 1) * 96] = 3e38f;
      }
      int j = 0;
      for (int q = 0; q < 96; q++) {
        while (Z[(j + 1) * 96] < (float)q) j++;
        int vj = Vv[j * 96];
        int dq = q - vj;
        int val = (int)dl[vj * LSTR + x] + dq * dq;
        D[q * SLICE + x] = (unsigned short)min(val, INF16);
      }
    }
  }
  __syncthreads();
  const unsigned short* D0 = dist + (size_t)(b * KK) * VOL + y * 96;
  const unsigned short* D1 = D0 + VOL;
  const unsigned short* D2 = D1 + VOL;
  const float* P = pred + (size_t)b * VOL + y * 96;
  const float* G = tgt + (size_t)b * VOL + y * 96;
  float s[9];
  #pragma unroll
  for (int q = 0; q < 9; q++) s[q] = 0.f;
  for (int i = t; i < SLICE; i += 256) {
    int zz = i / 96, xx = i - zz * 96;
    int off = zz * SLICE + xx;
    int d0 = D0[off], d1 = D1[off], d2 = D2[off];
    int kk = 0, dm = d0;
    if (d1 < dm) { kk = 1; dm = d1; }
    if (d2 < dm) kk = 2;
    float p = 1.f / (1.f + expf(-P[off]));
    float g = G[off];
    s[kk] += p * g;
    s[3 + kk] += p;
    s[6 + kk] += g;
  }
  #pragma unroll
  for (int off = 32; off > 0; off >>= 1)
    #pragma unroll
    for (int q = 0; q < 9; q++) s[q] += __shfl_down(s[q], off);
  int wave = t >> 6, lane = t & 63;
  if (lane == 0) {
    #pragma unroll
    for (int q = 0; q < 9; q++) wsum[wave][q] = s[q];
  }
  __syncthreads();
  if (t < 9)
    part[blk * 9 + t] = wsum[0][t] + wsum[1][t] + wsum[2][t] + wsum[3][t];
}

__global__ void k_finalize(const float* __restrict__ part, const int* __restrict__ ul,
                           float* __restrict__ out) {
  float a[18];
  #pragma unroll
  for (int q = 0; q < 18; q++) a[q] = 0.f;
  for (int r = threadIdx.x; r < NPART; r += 256) {
    int b = r / 96;
    #pragma unroll
    for (int q = 0; q < 9; q++) a[b * 9 + q] += part[r * 9 + q];
  }
  #pragma unroll
  for (int off = 32; off > 0; off >>= 1)
    #pragma unroll
    for (int q = 0; q < 18; q++) a[q] += __shfl_down(a[q], off);
  __shared__ float fs[4][18];
  int wave = threadIdx.x >> 6, lane = threadIdx.x & 63;
  if (lane == 0) {
    #pragma unroll
    for (int q = 0; q < 18; q++) fs[wave][q] = a[q];
  }
  __syncthreads();
  if (threadIdx.x == 0) {
    float tot[18];
    #pragma unroll
    for (int q = 0; q < 18; q++)
      tot[q] = fs[0][q] + fs[1][q] + fs[2][q] + fs[3][q];
    float loss = 0.f;
    for (int b = 0; b < NB; b++) {
      int cnt = 0;
      float ds = 0.f;
      for (int k = 0; k < KK; k++) {
        bool valid = ul[b * 4 + k] < BIGI;
        float inter = tot[b * 9 + k];
        float ps = tot[b * 9 + 3 + k];
        float gs = tot[b * 9 + 6 + k];
        float dice = 2.f * inter / (ps + gs + 1e-8f);
        if (valid) { ds += dice; cnt++; }
      }
      float mean = ds / fmaxf((float)cnt, 1.f);
      loss += (cnt > 0) ? (1.f - mean) : 1.f;
    }
    out[0] = loss * 0.5f;
  }
}

extern "C" void kernel_launch(void* const* d_in, const int* in_sizes, int n_in,
                              void* d_out, int out_size, void* d_ws, size_t ws_size,
                              hipStream_t stream) {
  const float* pred = (const float*)d_in[0];
  const float* tgt  = (const float*)d_in[1];
  float* out = (float*)d_out;

  char* ws = (char*)d_ws;
  int* lab   = (int*)(ws);
  int* act   = (int*)(ws + OFF_ACT);
  unsigned short* dist = (unsigned short*)(ws + OFF_DIST);
  int* small = (int*)(ws + OFF_SMALL);
  int* roots = (int*)(ws + OFF_ROOTS);
  int* ul    = (int*)(ws + OFF_UL);
  float* part = (float*)(ws + OFF_PART);

  k_zero_small<<<1, 64, 0, stream>>>(small);
  k_init<<<(NB * VOL + 255) / 256, 256, 0, stream>>>(tgt, lab, act, small);
  for (int it = 0; it < CC_SWEEPS; it++)
    k_prop<<<96, 256, 0, stream>>>(lab, act, small, it == CC_SWEEPS - 1 ? 1 : 0, roots);
  k_select<<<1, 64, 0, stream>>>(small, roots, ul);
  k_edt_xy<<<NB * 96, 256, 0, stream>>>(lab, ul, dist);
  k_edt_z_fuse<<<NB * 96, 256, 0, stream>>>(dist, pred, tgt, part);
  k_finalize<<<1, 256, 0, stream>>>(part, ul, out);
}

// Round 3
// 258.398 us; speedup vs baseline: 2.0445x; 2.0445x over previous
//
#include <hip/hip_runtime.h>
#include <math.h>

#define DIMN 96
#define SLICE 9216           // 96*96
#define VOL 884736           // 96^3
#define NB 2
#define KK 3
#define BIGI VOL             // reference BIGI = V
#define INF16 60000          // ushort "infinity"; real d^2 <= 3*95^2 = 27075
#define BIGD (1<<29)
#define LSTR 97              // padded LDS row stride
#define NPART 192
#define CC_SWEEPS 6          // reach R(t+1)=3R(t)+1 -> R(6)=364 >> 18 needed

// ---- workspace layout (bytes) ----
// lab:   NB*VOL*4       @0
// act:   NB*VOL*4       @OFF_ACT (only ~18k entries used)
// distA: NB*KK*VOL*2    @OFF_DIST, layout [(b*KK+k)][y][z][x] ushort
// small: 32             @OFF_SMALL ([0]=nact,[1]=roots_b0,[2]=roots_b1)
// roots: 2*64*4         @OFF_ROOTS
// flags: NB*KK*96*4     @OFF_FLAG  (slice-has-seed, indexed by z)
// part:  NPART*9*4      @OFF_PART
#define OFF_ACT   (NB*VOL*4)
#define OFF_DIST  (2*NB*VOL*4)
#define OFF_SMALL (OFF_DIST + NB*KK*VOL*2)
#define OFF_ROOTS (OFF_SMALL + 32)
#define OFF_FLAG  (OFF_ROOTS + 2*64*4)
#define OFF_PART  (OFF_FLAG + NB*KK*96*4)

__global__ void k_zero_small(int* small) {
  if (threadIdx.x < 8) small[threadIdx.x] = 0;
}

__global__ void k_init(const float* __restrict__ tgt, int* __restrict__ lab,
                       int* __restrict__ act, int* __restrict__ small) {
  int idx = blockIdx.x * 256 + threadIdx.x;
  if (idx >= NB * VOL) return;
  int v = (idx >= VOL) ? idx - VOL : idx;
  if (tgt[idx] > 0.5f) {
    lab[idx] = v;
    int pos = atomicAdd(&small[0], 1);
    act[pos] = idx;
  } else {
    lab[idx] = BIGI;
  }
}

// chaotic 27-neighbor min + double pointer-jump. Monotone; labels always
// valid same-component voxel indices; fixpoint = per-component min index.
__global__ void k_prop(int* __restrict__ lab, const int* __restrict__ act,
                       int* __restrict__ small, int record,
                       int* __restrict__ roots) {
  int n = small[0];
  for (int i = blockIdx.x * blockDim.x + threadIdx.x; i < n;
       i += gridDim.x * blockDim.x) {
    int idx = act[i];
    int bo = (idx >= VOL) ? VOL : 0;
    int v = idx - bo;
    int z = v / SLICE;
    int rem = v - z * SLICE;
    int y = rem / DIMN;
    int x = rem - y * DIMN;
    int* L = lab + bo;
    int z0 = z > 0 ? z - 1 : 0, z1 = z < 95 ? z + 1 : 95;
    int y0 = y > 0 ? y - 1 : 0, y1 = y < 95 ? y + 1 : 95;
    int x0 = x > 0 ? x - 1 : 0, x1 = x < 95 ? x + 1 : 95;
    int m = BIGI;
    for (int zz = z0; zz <= z1; zz++)
      for (int yy = y0; yy <= y1; yy++) {
        const int* row = L + zz * SLICE + yy * DIMN;
        for (int xx = x0; xx <= x1; xx++) m = min(m, row[xx]);
      }
    int m2 = L[m];
    int m3 = L[m2];
    lab[idx] = m3;
    if (record && m3 == v) {
      int b = bo ? 1 : 0;
      int pos = atomicAdd(&small[1 + b], 1);
      if (pos < 64) roots[b * 64 + pos] = v;
    }
  }
}

// One block per (b,z,k). Seed bitmasks -> O(1) x-EDT via bit scans ->
// y-pass brute force over valid rows only. Writes dist[(b*KK+k)][y][z][x]
// for slices that contain seeds; writes per-slice flag.
__global__ __launch_bounds__(256) void k_edt_xy(const int* __restrict__ lab,
                                                const int* __restrict__ small,
                                                const int* __restrict__ roots,
                                                unsigned short* __restrict__ distA,
                                                int* __restrict__ flags) {
  int blk = blockIdx.x;             // b*(96*KK) + z*KK + k
  int b = blk / (96 * KK);
  int rem = blk - b * 96 * KK;
  int z = rem / KK;
  int k = rem - z * KK;
  __shared__ unsigned long long mLo[96], mHi[96];
  __shared__ unsigned short dl[96 * LSTR];
  __shared__ unsigned short vrow[96];
  __shared__ int s_misc[2];         // [0]=ulk [1]=nValid
  __shared__ int s_roots[64];
  int t = threadIdx.x;
  int nr = small[1 + b];
  if (nr > 64) nr = 64;
  if (t < 64) s_roots[t] = (t < nr) ? roots[b * 64 + t] : 0x7fffffff;
  if (t < 96) { mLo[t] = 0; mHi[t] = 0; }
  if (t == 0) s_misc[0] = BIGI;
  __syncthreads();
  // k-th smallest root = the root whose rank among all roots equals k
  if (t < 64) {
    int r = s_roots[t];
    if (r != 0x7fffffff) {
      int rank = 0;
      #pragma unroll
      for (int j = 0; j < 64; j++) rank += (s_roots[j] < r) ? 1 : 0;
      if (rank == k) s_misc[0] = r;
    }
  }
  __syncthreads();
  int ulk = s_misc[0];
  const int* L = lab + b * VOL + z * SLICE;
  for (int i = t; i < SLICE; i += 256) {
    if (L[i] == ulk) {
      int y = i / 96, x = i - y * 96;
      if (x < 64) atomicOr(&mLo[y], 1ull << x);
      else        atomicOr(&mHi[y], 1ull << (x - 64));
    }
  }
  __syncthreads();
  if (t == 0) {
    int n = 0;
    for (int y = 0; y < 96; y++)
      if (mLo[y] | mHi[y]) vrow[n++] = (unsigned short)y;
    s_misc[1] = n;
    flags[(b * KK + k) * 96 + z] = (n > 0) ? 1 : 0;
  }
  __syncthreads();
  int nValid = s_misc[1];
  if (nValid == 0) return;
  // x-EDT: O(1) per voxel from the row bitmask
  for (int i = t; i < SLICE; i += 256) {
    int y = i / 96, x = i - y * 96;
    unsigned long long lo = mLo[y], hi = mHi[y];
    int dr, dlft;
    {
      unsigned long long rl, rh;
      if (x == 0)       { rl = lo; rh = hi; }
      else if (x < 64)  { rl = (lo >> x) | (hi << (64 - x)); rh = hi >> x; }
      else              { rl = hi >> (x - 64); rh = 0; }
      dr = rl ? (__ffsll(rl) - 1) : (rh ? (63 + __ffsll(rh)) : 1000);
    }
    {
      unsigned long long ll, lh;
      if (x >= 64) { ll = lo; lh = hi & ((2ull << (x - 64)) - 1); }
      else         { ll = lo & ((2ull << x) - 1); lh = 0; }
      dlft = lh ? (x - 127 + __clzll(lh))
                : (ll ? (x - 63 + __clzll(ll)) : 1000);
    }
    int d = min(dr, dlft);
    dl[y * LSTR + x] = (unsigned short)((d <= 95) ? d * d : INF16);
  }
  __syncthreads();
  // y-pass: brute force over valid rows only; 8 outputs/thread in regs
  unsigned short* DA = distA + (size_t)(b * KK + k) * VOL + (size_t)z * 96;
  for (int task = t; task < 1152; task += 256) {
    int x = task % 96;
    int y0 = (task / 96) * 8;
    int acc[8];
    #pragma unroll
    for (int i2 = 0; i2 < 8; i2++) acc[i2] = BIGD;
    for (int jj = 0; jj < nValid; jj++) {
      int j = vrow[jj];
      int f = dl[j * LSTR + x];
      int d0 = y0 - j;
      #pragma unroll
      for (int i2 = 0; i2 < 8; i2++) {
        int dd = d0 + i2;
        acc[i2] = min(acc[i2], f + dd * dd);
      }
    }
    #pragma unroll
    for (int i2 = 0; i2 < 8; i2++)
      DA[(size_t)(y0 + i2) * SLICE + x] = (unsigned short)min(acc[i2], INF16);
  }
}

// One block per (b,y): z-pass brute force over valid slices only (compact
// LDS), then argmin over k + sigmoid + dice partial sums, fused.
__global__ __launch_bounds__(256) void k_edt_z_fuse(const unsigned short* __restrict__ distA,
                                                    const int* __restrict__ flags,
                                                    const float* __restrict__ pred,
                                                    const float* __restrict__ tgt,
                                                    float* __restrict__ part) {
  int blk = blockIdx.x;   // b*96 + y
  int b = blk / 96, y = blk - b * 96;
  __shared__ unsigned short g[KK][96 * 96];   // [k][jj][x], compact valid z
  __shared__ unsigned char zl[KK][96];
  __shared__ int s_nz[KK];
  __shared__ float wsum[4][9];
  int t = threadIdx.x;
  if (t < KK) {
    const int* F = flags + (b * KK + t) * 96;
    int n = 0;
    for (int z = 0; z < 96; z++)
      if (F[z]) zl[t][n++] = (unsigned char)z;
    s_nz[t] = n;
  }
  __syncthreads();
  for (int k = 0; k < KK; k++) {
    int n = s_nz[k];
    const unsigned short* src = distA + (size_t)(b * KK + k) * VOL + (size_t)y * SLICE;
    for (int i = t; i < n * 96; i += 256) {
      int jj = i / 96, x = i - jj * 96;
      g[k][jj * 96 + x] = src[(size_t)zl[k][jj] * 96 + x];
    }
  }
  __syncthreads();
  const float* P = pred + (size_t)b * VOL + (size_t)y * 96;
  const float* G = tgt + (size_t)b * VOL + (size_t)y * 96;
  float s[9];
  #pragma unroll
  for (int q = 0; q < 9; q++) s[q] = 0.f;
  for (int i = t; i < SLICE; i += 256) {
    int z = i / 96, x = i - z * 96;
    int dk[KK];
    #pragma unroll
    for (int k = 0; k < KK; k++) {
      int n = s_nz[k];
      int best = BIGD;
      for (int jj = 0; jj < n; jj++) {
        int dz = z - (int)zl[k][jj];
        best = min(best, (int)g[k][jj * 96 + x] + dz * dz);
      }
      dk[k] = best;
    }
    int kk = 0, dm = dk[0];
    if (dk[1] < dm) { kk = 1; dm = dk[1]; }
    if (dk[2] < dm) kk = 2;
    int off = z * SLICE + x;
    float p = 1.f / (1.f + expf(-P[off]));
    float gg = G[off];
    s[kk] += p * gg;
    s[3 + kk] += p;
    s[6 + kk] += gg;
  }
  #pragma unroll
  for (int off = 32; off > 0; off >>= 1)
    #pragma unroll
    for (int q = 0; q < 9; q++) s[q] += __shfl_down(s[q], off);
  int wave = t >> 6, lane = t & 63;
  if (lane == 0) {
    #pragma unroll
    for (int q = 0; q < 9; q++) wsum[wave][q] = s[q];
  }
  __syncthreads();
  if (t < 9)
    part[blk * 9 + t] = wsum[0][t] + wsum[1][t] + wsum[2][t] + wsum[3][t];
}

__global__ void k_finalize(const float* __restrict__ part, const int* __restrict__ small,
                           float* __restrict__ out) {
  float a[18];
  #pragma unroll
  for (int q = 0; q < 18; q++) a[q] = 0.f;
  for (int r = threadIdx.x; r < NPART; r += 256) {
    int b = r / 96;
    #pragma unroll
    for (int q = 0; q < 9; q++) a[b * 9 + q] += part[r * 9 + q];
  }
  #pragma unroll
  for (int off = 32; off > 0; off >>= 1)
    #pragma unroll
    for (int q = 0; q < 18; q++) a[q] += __shfl_down(a[q], off);
  __shared__ float fs[4][18];
  int wave = threadIdx.x >> 6, lane = threadIdx.x & 63;
  if (lane == 0) {
    #pragma unroll
    for (int q = 0; q < 18; q++) fs[wave][q] = a[q];
  }
  __syncthreads();
  if (threadIdx.x == 0) {
    float tot[18];
    #pragma unroll
    for (int q = 0; q < 18; q++)
      tot[q] = fs[0][q] + fs[1][q] + fs[2][q] + fs[3][q];
    float loss = 0.f;
    for (int b = 0; b < NB; b++) {
      int cnt = small[1 + b];
      if (cnt > KK) cnt = KK;       // valid k's are exactly the first cnt
      float ds = 0.f;
      for (int k = 0; k < cnt; k++) {
        float inter = tot[b * 9 + k];
        float ps = tot[b * 9 + 3 + k];
        float gs = tot[b * 9 + 6 + k];
        ds += 2.f * inter / (ps + gs + 1e-8f);
      }
      float mean = ds / fmaxf((float)cnt, 1.f);
      loss += (cnt > 0) ? (1.f - mean) : 1.f;
    }
    out[0] = loss * 0.5f;
  }
}

extern "C" void kernel_launch(void* const* d_in, const int* in_sizes, int n_in,
                              void* d_out, int out_size, void* d_ws, size_t ws_size,
                              hipStream_t stream) {
  const float* pred = (const float*)d_in[0];
  const float* tgt  = (const float*)d_in[1];
  float* out = (float*)d_out;

  char* ws = (char*)d_ws;
  int* lab   = (int*)(ws);
  int* act   = (int*)(ws + OFF_ACT);
  unsigned short* distA = (unsigned short*)(ws + OFF_DIST);
  int* small = (int*)(ws + OFF_SMALL);
  int* roots = (int*)(ws + OFF_ROOTS);
  int* flags = (int*)(ws + OFF_FLAG);
  float* part = (float*)(ws + OFF_PART);

  k_zero_small<<<1, 64, 0, stream>>>(small);
  k_init<<<(NB * VOL + 255) / 256, 256, 0, stream>>>(tgt, lab, act, small);
  for (int it = 0; it < CC_SWEEPS; it++)
    k_prop<<<96, 256, 0, stream>>>(lab, act, small, it == CC_SWEEPS - 1 ? 1 : 0, roots);
  k_edt_xy<<<NB * 96 * KK, 256, 0, stream>>>(lab, small, roots, distA, flags);
  k_edt_z_fuse<<<NB * 96, 256, 0, stream>>>(distA, flags, pred, tgt, part);
  k_finalize<<<1, 256, 0, stream>>>(part, small, out);
}

// Round 4
// 221.871 us; speedup vs baseline: 2.3811x; 1.1646x over previous
//
#include <hip/hip_runtime.h>
#include <math.h>

#define DIMN 96
#define SLICE 9216           // 96*96
#define VOL 884736           // 96^3
#define NB 2
#define KK 3
#define BIGI VOL             // reference BIGI = V
#define BIGP 0x3FFFFFFC      // packed "infinity" (low 2 label bits = 0)
#define NPART 192
#define CC_SWEEPS 5          // reach >= 3R+1 per sweep -> 121 >> 18 needed

// ---- workspace layout (bytes) ----
// lab:   NB*VOL*4    @0
// act:   NB*VOL*4    @OFF_ACT (only ~18k entries used)
// distP: NB*VOL*4    @OFF_DIST, packed (d2<<2|k), layout [b][y][z][x]
// small: 32          @OFF_SMALL ([0]=nact,[1]=roots_b0,[2]=roots_b1)
// roots: 2*64*4      @OFF_ROOTS
// flags: NB*96*4     @OFF_FLAG  (slice z has any seed)
// part:  NPART*9*4   @OFF_PART
#define OFF_ACT   (NB*VOL*4)
#define OFF_DIST  (2*NB*VOL*4)
#define OFF_SMALL (OFF_DIST + NB*VOL*4)
#define OFF_ROOTS (OFF_SMALL + 32)
#define OFF_FLAG  (OFF_ROOTS + 2*64*4)
#define OFF_PART  (OFF_FLAG + NB*96*4)

__global__ void k_zero_small(int* small) {
  if (threadIdx.x < 8) small[threadIdx.x] = 0;
}

__global__ void k_init(const float* __restrict__ tgt, int* __restrict__ lab,
                       int* __restrict__ act, int* __restrict__ small) {
  int idx = blockIdx.x * 256 + threadIdx.x;
  if (idx >= NB * VOL) return;
  int v = (idx >= VOL) ? idx - VOL : idx;
  if (tgt[idx] > 0.5f) {
    lab[idx] = v;
    int pos = atomicAdd(&small[0], 1);
    act[pos] = idx;
  } else {
    lab[idx] = BIGI;
  }
}

// chaotic 27-neighbor min + double pointer-jump (validated exact in R2/R3).
__global__ void k_prop(int* __restrict__ lab, const int* __restrict__ act,
                       int* __restrict__ small, int record,
                       int* __restrict__ roots) {
  int n = small[0];
  for (int i = blockIdx.x * blockDim.x + threadIdx.x; i < n;
       i += gridDim.x * blockDim.x) {
    int idx = act[i];
    int bo = (idx >= VOL) ? VOL : 0;
    int v = idx - bo;
    int z = v / SLICE;
    int rem = v - z * SLICE;
    int y = rem / DIMN;
    int x = rem - y * DIMN;
    int* L = lab + bo;
    int z0 = z > 0 ? z - 1 : 0, z1 = z < 95 ? z + 1 : 95;
    int y0 = y > 0 ? y - 1 : 0, y1 = y < 95 ? y + 1 : 95;
    int x0 = x > 0 ? x - 1 : 0, x1 = x < 95 ? x + 1 : 95;
    int m = BIGI;
    for (int zz = z0; zz <= z1; zz++)
      for (int yy = y0; yy <= y1; yy++) {
        const int* row = L + zz * SLICE + yy * DIMN;
        for (int xx = x0; xx <= x1; xx++) m = min(m, row[xx]);
      }
    int m2 = L[m];
    int m3 = L[m2];
    lab[idx] = m3;
    if (record && m3 == v) {
      int b = bo ? 1 : 0;
      int pos = atomicAdd(&small[1 + b], 1);
      if (pos < 64) roots[b * 64 + pos] = v;
    }
  }
}

// nearest-seed distance in a 96-wide row encoded as a 128-bit mask (O(1))
__device__ __forceinline__ int row_dist(unsigned long long lo,
                                        unsigned long long hi, int x) {
  int dr, dlft;
  {
    unsigned long long rl, rh;
    if (x == 0)      { rl = lo; rh = hi; }
    else if (x < 64) { rl = (lo >> x) | (hi << (64 - x)); rh = hi >> x; }
    else             { rl = hi >> (x - 64); rh = 0; }
    dr = rl ? (__ffsll(rl) - 1) : (rh ? (63 + __ffsll(rh)) : 1000);
  }
  {
    unsigned long long ll, lh;
    if (x >= 64) { ll = lo; lh = hi & ((2ull << (x - 64)) - 1); }
    else         { ll = lo & ((2ull << x) - 1); lh = 0; }
    dlft = lh ? (x - 127 + __clzll(lh))
              : (ll ? (x - 63 + __clzll(ll)) : 1000);
  }
  return min(dr, dlft);
}

// One block per (b,z): labeled-union x-pass (bitmask O(1)) + y-pass brute
// force over seed-bearing rows only, values packed (d2<<2|k) so integer min
// == lexicographic (dist, k) == jnp.argmin tie-break. Writes [b][y][z][x].
__global__ __launch_bounds__(256) void k_edt_xy(const int* __restrict__ lab,
                                                const int* __restrict__ small,
                                                const int* __restrict__ roots,
                                                int* __restrict__ distP,
                                                int* __restrict__ flags) {
  int blk = blockIdx.x;             // b*96 + z
  int b = blk / 96, z = blk - b * 96;
  __shared__ unsigned long long mLo[KK][96], mHi[KK][96];
  __shared__ int pl[SLICE];
  __shared__ unsigned char vrow[96];
  __shared__ int s_roots[64];
  __shared__ int s_ul[KK];
  __shared__ int s_n;
  int t = threadIdx.x;
  int nr = small[1 + b];
  if (nr > 64) nr = 64;
  if (t < 64) s_roots[t] = (t < nr) ? roots[b * 64 + t] : 0x7fffffff;
  if (t < KK) s_ul[t] = -1;         // no match possible if fewer roots
  for (int i = t; i < KK * 96; i += 256) { mLo[0][i] = 0; mHi[0][i] = 0; }
  __syncthreads();
  if (t < 64) {                     // k-th smallest root by rank
    int r = s_roots[t];
    if (r != 0x7fffffff) {
      int rank = 0;
      #pragma unroll
      for (int j = 0; j < 64; j++) rank += (s_roots[j] < r) ? 1 : 0;
      if (rank < KK) s_ul[rank] = r;
    }
  }
  __syncthreads();
  int ul0 = s_ul[0], ul1 = s_ul[1], ul2 = s_ul[2];
  const int* L = lab + b * VOL + z * SLICE;
  for (int i = t; i < SLICE; i += 256) {
    int lv = L[i];
    if (lv < BIGI) {
      int k = (lv == ul0) ? 0 : (lv == ul1) ? 1 : (lv == ul2) ? 2 : -1;
      if (k >= 0) {
        int y = i / 96, x = i - y * 96;
        if (x < 64) atomicOr(&mLo[k][y], 1ull << x);
        else        atomicOr(&mHi[k][y], 1ull << (x - 64));
      }
    }
  }
  __syncthreads();
  if (t == 0) {
    int n = 0;
    for (int y = 0; y < 96; y++)
      if (mLo[0][y] | mHi[0][y] | mLo[1][y] | mHi[1][y] | mLo[2][y] | mHi[2][y])
        vrow[n++] = (unsigned char)y;
    s_n = n;
    flags[b * 96 + z] = (n > 0) ? 1 : 0;
  }
  __syncthreads();
  int nValid = s_n;
  if (nValid == 0) return;
  // x-pass: packed min over k, O(1) per (voxel,k)
  for (int i = t; i < SLICE; i += 256) {
    int y = i / 96, x = i - y * 96;
    int best = BIGP;
    #pragma unroll
    for (int k = 0; k < KK; k++) {
      unsigned long long lo = mLo[k][y], hi = mHi[k][y];
      if (lo | hi) {
        int d = row_dist(lo, hi, x);
        best = min(best, ((d * d) << 2) | k);
      }
    }
    pl[i] = best;
  }
  __syncthreads();
  // y-pass over seed rows only; 8 outputs/thread reuse each LDS read
  int* DA = distP + b * VOL + z * 96;
  for (int tt = t; tt < 1152; tt += 256) {
    int x = tt % 96;
    int y0 = (tt / 96) * 8;
    int acc[8];
    #pragma unroll
    for (int i2 = 0; i2 < 8; i2++) acc[i2] = BIGP;
    for (int jj = 0; jj < nValid; jj++) {
      int j = vrow[jj];
      int f = pl[j * 96 + x];
      int d0 = y0 - j;
      #pragma unroll
      for (int i2 = 0; i2 < 8; i2++) {
        int dy = d0 + i2;
        acc[i2] = min(acc[i2], f + ((dy * dy) << 2));
      }
    }
    #pragma unroll
    for (int i2 = 0; i2 < 8; i2++)
      DA[(y0 + i2) * SLICE + x] = acc[i2];
  }
}

// One block per (b,y): z-pass over valid slices only, 16 z-outputs per
// thread reusing each LDS read; then sigmoid + dice partials inline.
__global__ __launch_bounds__(256) void k_z_fuse(const int* __restrict__ distP,
                                                const int* __restrict__ flags,
                                                const float* __restrict__ pred,
                                                const float* __restrict__ tgt,
                                                float* __restrict__ part) {
  int blk = blockIdx.x;   // b*96 + y
  int b = blk / 96, y = blk - b * 96;
  __shared__ int g[SLICE];          // compact [jj][x]
  __shared__ unsigned char zl[96];
  __shared__ int s_nz;
  __shared__ float wsum[4][9];
  int t = threadIdx.x;
  if (t == 0) {
    const int* F = flags + b * 96;
    int n = 0;
    for (int z = 0; z < 96; z++)
      if (F[z]) zl[n++] = (unsigned char)z;
    s_nz = n;
  }
  __syncthreads();
  int nz = s_nz;
  const int* DP = distP + b * VOL + y * SLICE;
  for (int i = t; i < nz * 96; i += 256) {
    int jj = i / 96, x = i - jj * 96;
    g[i] = DP[(int)zl[jj] * 96 + x];
  }
  __syncthreads();
  const float* P = pred + (size_t)b * VOL + y * 96;
  const float* G = tgt + (size_t)b * VOL + y * 96;
  float s[9];
  #pragma unroll
  for (int q = 0; q < 9; q++) s[q] = 0.f;
  for (int tt = t; tt < 576; tt += 256) {
    int x = tt % 96;
    int z0 = (tt / 96) * 16;
    int acc[16];
    #pragma unroll
    for (int i2 = 0; i2 < 16; i2++) acc[i2] = BIGP;
    for (int jj = 0; jj < nz; jj++) {
      int f = g[jj * 96 + x];
      int d0 = z0 - (int)zl[jj];
      #pragma unroll
      for (int i2 = 0; i2 < 16; i2++) {
        int dz = d0 + i2;
        acc[i2] = min(acc[i2], f + ((dz * dz) << 2));
      }
    }
    #pragma unroll
    for (int i2 = 0; i2 < 16; i2++) {
      int off = (z0 + i2) * SLICE + x;
      float p = 1.f / (1.f + expf(-P[off]));
      float gg = G[off];
      int k = acc[i2] & 3;          // BIGP&3==0: safe when nz==0
      s[k] += p * gg;
      s[3 + k] += p;
      s[6 + k] += gg;
    }
  }
  #pragma unroll
  for (int off = 32; off > 0; off >>= 1)
    #pragma unroll
    for (int q = 0; q < 9; q++) s[q] += __shfl_down(s[q], off);
  int wave = t >> 6, lane = t & 63;
  if (lane == 0) {
    #pragma unroll
    for (int q = 0; q < 9; q++) wsum[wave][q] = s[q];
  }
  __syncthreads();
  if (t < 9)
    part[blk * 9 + t] = wsum[0][t] + wsum[1][t] + wsum[2][t] + wsum[3][t];
}

__global__ void k_finalize(const float* __restrict__ part, const int* __restrict__ small,
                           float* __restrict__ out) {
  float a[18];
  #pragma unroll
  for (int q = 0; q < 18; q++) a[q] = 0.f;
  for (int r = threadIdx.x; r < NPART; r += 256) {
    int b = r / 96;
    #pragma unroll
    for (int q = 0; q < 9; q++) a[b * 9 + q] += part[r * 9 + q];
  }
  #pragma unroll
  for (int off = 32; off > 0; off >>= 1)
    #pragma unroll
    for (int q = 0; q < 18; q++) a[q] += __shfl_down(a[q], off);
  __shared__ float fs[4][18];
  int wave = threadIdx.x >> 6, lane = threadIdx.x & 63;
  if (lane == 0) {
    #pragma unroll
    for (int q = 0; q < 18; q++) fs[wave][q] = a[q];
  }
  __syncthreads();
  if (threadIdx.x == 0) {
    float tot[18];
    #pragma unroll
    for (int q = 0; q < 18; q++)
      tot[q] = fs[0][q] + fs[1][q] + fs[2][q] + fs[3][q];
    float loss = 0.f;
    for (int b = 0; b < NB; b++) {
      int cnt = small[1 + b];
      if (cnt > KK) cnt = KK;
      float ds = 0.f;
      for (int k = 0; k < cnt; k++) {
        float inter = tot[b * 9 + k];
        float ps = tot[b * 9 + 3 + k];
        float gs = tot[b * 9 + 6 + k];
        ds += 2.f * inter / (ps + gs + 1e-8f);
      }
      float mean = ds / fmaxf((float)cnt, 1.f);
      loss += (cnt > 0) ? (1.f - mean) : 1.f;
    }
    out[0] = loss * 0.5f;
  }
}

extern "C" void kernel_launch(void* const* d_in, const int* in_sizes, int n_in,
                              void* d_out, int out_size, void* d_ws, size_t ws_size,
                              hipStream_t stream) {
  const float* pred = (const float*)d_in[0];
  const float* tgt  = (const float*)d_in[1];
  float* out = (float*)d_out;

  char* ws = (char*)d_ws;
  int* lab   = (int*)(ws);
  int* act   = (int*)(ws + OFF_ACT);
  int* distP = (int*)(ws + OFF_DIST);
  int* small = (int*)(ws + OFF_SMALL);
  int* roots = (int*)(ws + OFF_ROOTS);
  int* flags = (int*)(ws + OFF_FLAG);
  float* part = (float*)(ws + OFF_PART);

  k_zero_small<<<1, 64, 0, stream>>>(small);
  k_init<<<(NB * VOL + 255) / 256, 256, 0, stream>>>(tgt, lab, act, small);
  for (int it = 0; it < CC_SWEEPS; it++)
    k_prop<<<96, 256, 0, stream>>>(lab, act, small, it == CC_SWEEPS - 1 ? 1 : 0, roots);
  k_edt_xy<<<NB * 96, 256, 0, stream>>>(lab, small, roots, distP, flags);
  k_z_fuse<<<NB * 96, 256, 0, stream>>>(distP, flags, pred, tgt, part);
  k_finalize<<<1, 256, 0, stream>>>(part, small, out);
}

// Round 5
// 182.599 us; speedup vs baseline: 2.8932x; 1.2151x over previous
//
#include <hip/hip_runtime.h>
#include <math.h>

#define SLICE 9216           // 96*96
#define VOL 884736           // 96^3
#define NB 2
#define KK 3
#define BIGI VOL             // reference BIGI = V
#define BIGP 0x3FFFFFFC      // packed "infinity" (low 2 label bits = 0)
#define CC_SWEEPS 5          // chaotic + double pointer-jump; validated exact R3/R4
#define YCH 16
#define NYC 6                // 96/YCH
#define ZCH 24
#define NZC 4                // 96/ZCH
#define NPART (NB*96*NZC)    // 768

// ---- workspace layout (bytes) ----
// lab:   NB*VOL*4        @0
// act:   NB*VOL*4        @OFF_ACT (only ~18k entries used)
// distP: NB*VOL*4        @OFF_DIST, packed (d2<<2|k), layout [b][y][z][x]
// small: 32              @OFF_SMALL ([0]=nact,[1]=roots_b0,[2]=roots_b1)
// roots: 2*64*4          @OFF_ROOTS
// masks: NB*KK*96*96*16  @OFF_MASK  seed row bitmask [b][k][z][y]{lo,hi}
// zflag: NB*96*4         @OFF_ZFLAG (slice z has any seed; written by k_edt_xy)
// part:  NPART*9*4       @OFF_PART
#define OFF_ACT   (NB*VOL*4)
#define OFF_DIST  (2*NB*VOL*4)
#define OFF_SMALL (OFF_DIST + NB*VOL*4)
#define OFF_ROOTS (OFF_SMALL + 32)
#define OFF_MASK  (OFF_ROOTS + 512)
#define MASK_BYTES (NB*KK*96*96*16)
#define OFF_ZFLAG (OFF_MASK + MASK_BYTES)
#define OFF_PART  (OFF_ZFLAG + NB*96*4)
#define ZERO_BYTES (32 + 512 + MASK_BYTES)   // small+roots+masks, one memset

__global__ void k_init(const float* __restrict__ tgt, int* __restrict__ lab,
                       int* __restrict__ act, int* __restrict__ small) {
  int idx = blockIdx.x * 256 + threadIdx.x;
  if (idx >= NB * VOL) return;
  int v = (idx >= VOL) ? idx - VOL : idx;
  if (tgt[idx] > 0.5f) {
    lab[idx] = v;
    int pos = atomicAdd(&small[0], 1);
    act[pos] = idx;
  } else {
    lab[idx] = BIGI;
  }
}

// chaotic 27-neighbor min + double pointer-jump (validated exact in R2-R4).
__global__ void k_prop(int* __restrict__ lab, const int* __restrict__ act,
                       int* __restrict__ small, int record,
                       int* __restrict__ roots) {
  int n = small[0];
  for (int i = blockIdx.x * blockDim.x + threadIdx.x; i < n;
       i += gridDim.x * blockDim.x) {
    int idx = act[i];
    int bo = (idx >= VOL) ? VOL : 0;
    int v = idx - bo;
    int z = v / SLICE;
    int rem = v - z * SLICE;
    int y = rem / 96;
    int x = rem - y * 96;
    int* L = lab + bo;
    int z0 = z > 0 ? z - 1 : 0, z1 = z < 95 ? z + 1 : 95;
    int y0 = y > 0 ? y - 1 : 0, y1 = y < 95 ? y + 1 : 95;
    int x0 = x > 0 ? x - 1 : 0, x1 = x < 95 ? x + 1 : 95;
    int m = BIGI;
    for (int zz = z0; zz <= z1; zz++)
      for (int yy = y0; yy <= y1; yy++) {
        const int* row = L + zz * SLICE + yy * 96;
        for (int xx = x0; xx <= x1; xx++) m = min(m, row[xx]);
      }
    int m2 = L[m];
    int m3 = L[m2];
    lab[idx] = m3;
    if (record && m3 == v) {
      int b = bo ? 1 : 0;
      int pos = atomicAdd(&small[1 + b], 1);
      if (pos < 64) roots[b * 64 + pos] = v;
    }
  }
}

// rank roots -> ul per batch (in-block, redundant per block = cheap), then
// scatter seed bits into global row masks [b][k][z][y]{lo,hi} via atomicOr.
__global__ void k_seeds(const int* __restrict__ lab, const int* __restrict__ act,
                        const int* __restrict__ small, const int* __restrict__ roots,
                        unsigned long long* __restrict__ masks) {
  __shared__ int s_roots[128];
  __shared__ int s_ul[NB][KK];
  int t = threadIdx.x;
  if (t < 128) {
    int b = t >> 6, j = t & 63;
    int nr = small[1 + b]; if (nr > 64) nr = 64;
    s_roots[t] = (j < nr) ? roots[t] : 0x7fffffff;
  }
  if (t < NB * KK) s_ul[t / KK][t % KK] = -1;
  __syncthreads();
  if (t < 128) {
    int r = s_roots[t];
    if (r != 0x7fffffff) {
      int b = t >> 6;
      int rank = 0;
      #pragma unroll
      for (int j = 0; j < 64; j++) rank += (s_roots[(b << 6) + j] < r) ? 1 : 0;
      if (rank < KK) s_ul[b][rank] = r;
    }
  }
  __syncthreads();
  int n = small[0];
  for (int i = blockIdx.x * 256 + t; i < n; i += gridDim.x * 256) {
    int idx = act[i];
    int b = (idx >= VOL) ? 1 : 0;
    int v = idx - (b ? VOL : 0);
    int lv = lab[idx];
    int k = (lv == s_ul[b][0]) ? 0 : (lv == s_ul[b][1]) ? 1
          : (lv == s_ul[b][2]) ? 2 : -1;
    if (k >= 0) {
      int z = v / SLICE;
      int rem = v - z * SLICE;
      int y = rem / 96;
      int x = rem - y * 96;
      unsigned long long* M = masks + (((size_t)(b * KK + k) * 96 + z) * 96 + y) * 2;
      if (x < 64) atomicOr(&M[0], 1ull << x);
      else        atomicOr(&M[1], 1ull << (x - 64));
    }
  }
}

// nearest-seed distance in a 96-wide row encoded as a 128-bit mask (O(1))
__device__ __forceinline__ int row_dist(unsigned long long lo,
                                        unsigned long long hi, int x) {
  int dr, dlft;
  {
    unsigned long long rl, rh;
    if (x == 0)      { rl = lo; rh = hi; }
    else if (x < 64) { rl = (lo >> x) | (hi << (64 - x)); rh = hi >> x; }
    else             { rl = hi >> (x - 64); rh = 0; }
    dr = rl ? (__ffsll(rl) - 1) : (rh ? (63 + __ffsll(rh)) : 1000);
  }
  {
    unsigned long long ll, lh;
    if (x >= 64) { ll = lo; lh = hi & ((2ull << (x - 64)) - 1); }
    else         { ll = lo & ((2ull << x) - 1); lh = 0; }
    dlft = lh ? (x - 127 + __clzll(lh))
              : (ll ? (x - 63 + __clzll(ll)) : 1000);
  }
  return min(dr, dlft);
}

// One block per (b, z, y-chunk of 16). Stage masks (4.6KB), x-pass O(1) per
// (row,k) via bit scans for seed rows only, y-pass brute force over seed
// rows with 8-way register reuse. Packed (d2<<2|k) min == (dist,k) lex min.
__global__ __launch_bounds__(256) void k_edt_xy(const unsigned long long* __restrict__ masks,
                                                int* __restrict__ distP,
                                                int* __restrict__ zflag) {
  int blk = blockIdx.x;             // b*(96*NYC) + z*NYC + yc
  int b = blk / (96 * NYC);
  int rem = blk - b * 96 * NYC;
  int z = rem / NYC;
  int yc = rem - z * NYC;
  __shared__ unsigned long long sM[KK * 192];   // [k][y][{lo,hi}]
  __shared__ int pl[SLICE];                     // [jj][x], jj < n seed rows
  __shared__ unsigned char vrow[96];
  __shared__ int s_n;
  int t = threadIdx.x;
  if (t == 0) s_n = 0;
  for (int i = t; i < KK * 192; i += 256) {
    int k = i / 192, r = i - k * 192;
    sM[i] = masks[((size_t)(b * KK + k) * 96 + z) * 192 + r];
  }
  __syncthreads();
  if (t < 96) {
    unsigned long long any = sM[t * 2] | sM[t * 2 + 1] | sM[192 + t * 2] |
                             sM[193 + t * 2] | sM[384 + t * 2] | sM[385 + t * 2];
    if (any) { int pos = atomicAdd(&s_n, 1); vrow[pos] = (unsigned char)t; }
  }
  __syncthreads();
  int n = s_n;
  if (t == 0 && yc == 0) zflag[b * 96 + z] = (n > 0) ? 1 : 0;
  if (n == 0) return;
  // x-pass for seed rows only
  for (int i = t; i < n * 96; i += 256) {
    int jj = i / 96, x = i - jj * 96;
    int y = vrow[jj];
    int best = BIGP;
    #pragma unroll
    for (int k = 0; k < KK; k++) {
      unsigned long long lo = sM[k * 192 + y * 2], hi = sM[k * 192 + y * 2 + 1];
      if (lo | hi) {
        int d = row_dist(lo, hi, x);
        best = min(best, ((d * d) << 2) | k);
      }
    }
    pl[jj * 96 + x] = best;
  }
  __syncthreads();
  // y-pass: 192 tasks (96 x * 2 y-groups of 8); each LDS read reused 8x
  if (t < 192) {
    int x = t % 96;
    int yg = t / 96;
    int yy0 = yc * YCH + yg * 8;
    int acc[8];
    #pragma unroll
    for (int i2 = 0; i2 < 8; i2++) acc[i2] = BIGP;
    for (int jj = 0; jj < n; jj++) {
      int j = vrow[jj];
      int f = pl[jj * 96 + x];
      int d0 = yy0 - j;
      #pragma unroll
      for (int i2 = 0; i2 < 8; i2++) {
        int dy = d0 + i2;
        acc[i2] = min(acc[i2], f + ((dy * dy) << 2));
      }
    }
    int* DA = distP + b * VOL + z * 96 + x;
    #pragma unroll
    for (int i2 = 0; i2 < 8; i2++)
      DA[(yy0 + i2) * SLICE] = acc[i2];
  }
}

// One block per (b, y, z-quarter). z-pass over valid slices (compact LDS)
// with 8-way register reuse, fused sigmoid + dice partials.
__global__ __launch_bounds__(256) void k_z_fuse(const int* __restrict__ distP,
                                                const int* __restrict__ zflag,
                                                const float* __restrict__ pred,
                                                const float* __restrict__ tgt,
                                                float* __restrict__ part) {
  int blk = blockIdx.x;             // b*(96*NZC) + y*NZC + zc
  int b = blk / (96 * NZC);
  int rem = blk - b * 96 * NZC;
  int y = rem / NZC;
  int zc = rem - y * NZC;
  __shared__ int g[SLICE];          // compact [jj][x]
  __shared__ unsigned char zl[96];
  __shared__ int s_nz;
  __shared__ float wsum[4][9];
  int t = threadIdx.x;
  if (t == 0) s_nz = 0;
  __syncthreads();
  if (t < 96) {
    if (zflag[b * 96 + t]) { int pos = atomicAdd(&s_nz, 1); zl[pos] = (unsigned char)t; }
  }
  __syncthreads();
  int nz = s_nz;
  const int* DP = distP + b * VOL + y * SLICE;
  for (int i = t; i < nz * 96; i += 256) {
    int jj = i / 96, x = i - jj * 96;
    g[i] = DP[(int)zl[jj] * 96 + x];
  }
  __syncthreads();
  const float* P = pred + (size_t)b * VOL + y * 96;
  const float* G = tgt + (size_t)b * VOL + y * 96;
  float s[9];
  #pragma unroll
  for (int q = 0; q < 9; q++) s[q] = 0.f;
  for (int tt = t; tt < 288; tt += 256) {   // 96 x * 3 z-groups of 8
    int x = tt % 96;
    int zg = tt / 96;
    int zz0 = zc * ZCH + zg * 8;
    int acc[8];
    #pragma unroll
    for (int i2 = 0; i2 < 8; i2++) acc[i2] = BIGP;
    for (int jj = 0; jj < nz; jj++) {
      int f = g[jj * 96 + x];
      int d0 = zz0 - (int)zl[jj];
      #pragma unroll
      for (int i2 = 0; i2 < 8; i2++) {
        int dz = d0 + i2;
        acc[i2] = min(acc[i2], f + ((dz * dz) << 2));
      }
    }
    #pragma unroll
    for (int i2 = 0; i2 < 8; i2++) {
      int off = (zz0 + i2) * SLICE + x;
      float p = 1.f / (1.f + expf(-P[off]));
      float gg = G[off];
      int k = acc[i2] & 3;          // BIGP&3==0: safe when nz==0
      s[k] += p * gg;
      s[3 + k] += p;
      s[6 + k] += gg;
    }
  }
  #pragma unroll
  for (int off = 32; off > 0; off >>= 1)
    #pragma unroll
    for (int q = 0; q < 9; q++) s[q] += __shfl_down(s[q], off);
  int wave = t >> 6, lane = t & 63;
  if (lane == 0) {
    #pragma unroll
    for (int q = 0; q < 9; q++) wsum[wave][q] = s[q];
  }
  __syncthreads();
  if (t < 9)
    part[blk * 9 + t] = wsum[0][t] + wsum[1][t] + wsum[2][t] + wsum[3][t];
}

__global__ void k_finalize(const float* __restrict__ part, const int* __restrict__ small,
                           float* __restrict__ out) {
  float a[18];
  #pragma unroll
  for (int q = 0; q < 18; q++) a[q] = 0.f;
  for (int r = threadIdx.x; r < NPART; r += 256) {
    int b = r / (96 * NZC);
    #pragma unroll
    for (int q = 0; q < 9; q++) a[b * 9 + q] += part[r * 9 + q];
  }
  #pragma unroll
  for (int off = 32; off > 0; off >>= 1)
    #pragma unroll
    for (int q = 0; q < 18; q++) a[q] += __shfl_down(a[q], off);
  __shared__ float fs[4][18];
  int wave = threadIdx.x >> 6, lane = threadIdx.x & 63;
  if (lane == 0) {
    #pragma unroll
    for (int q = 0; q < 18; q++) fs[wave][q] = a[q];
  }
  __syncthreads();
  if (threadIdx.x == 0) {
    float tot[18];
    #pragma unroll
    for (int q = 0; q < 18; q++)
      tot[q] = fs[0][q] + fs[1][q] + fs[2][q] + fs[3][q];
    float loss = 0.f;
    for (int b = 0; b < NB; b++) {
      int cnt = small[1 + b];
      if (cnt > KK) cnt = KK;
      float ds = 0.f;
      for (int k = 0; k < cnt; k++) {
        float inter = tot[b * 9 + k];
        float ps = tot[b * 9 + 3 + k];
        float gs = tot[b * 9 + 6 + k];
        ds += 2.f * inter / (ps + gs + 1e-8f);
      }
      float mean = ds / fmaxf((float)cnt, 1.f);
      loss += (cnt > 0) ? (1.f - mean) : 1.f;
    }
    out[0] = loss * 0.5f;
  }
}

extern "C" void kernel_launch(void* const* d_in, const int* in_sizes, int n_in,
                              void* d_out, int out_size, void* d_ws, size_t ws_size,
                              hipStream_t stream) {
  const float* pred = (const float*)d_in[0];
  const float* tgt  = (const float*)d_in[1];
  float* out = (float*)d_out;

  char* ws = (char*)d_ws;
  int* lab   = (int*)(ws);
  int* act   = (int*)(ws + OFF_ACT);
  int* distP = (int*)(ws + OFF_DIST);
  int* small = (int*)(ws + OFF_SMALL);
  int* roots = (int*)(ws + OFF_ROOTS);
  unsigned long long* masks = (unsigned long long*)(ws + OFF_MASK);
  int* zflag = (int*)(ws + OFF_ZFLAG);
  float* part = (float*)(ws + OFF_PART);

  hipMemsetAsync(ws + OFF_SMALL, 0, ZERO_BYTES, stream);  // small+roots+masks
  k_init<<<(NB * VOL + 255) / 256, 256, 0, stream>>>(tgt, lab, act, small);
  for (int it = 0; it < CC_SWEEPS; it++)
    k_prop<<<96, 256, 0, stream>>>(lab, act, small, it == CC_SWEEPS - 1 ? 1 : 0, roots);
  k_seeds<<<96, 256, 0, stream>>>(lab, act, small, roots, masks);
  k_edt_xy<<<NB * 96 * NYC, 256, 0, stream>>>(masks, distP, zflag);
  k_z_fuse<<<NB * 96 * NZC, 256, 0, stream>>>(distP, zflag, pred, tgt, part);
  k_finalize<<<1, 256, 0, stream>>>(part, small, out);
}